// Round 5
// baseline (982.448 us; speedup 1.0000x reference)
//
#include <hip/hip_runtime.h>

#define NN 50000
#define EE 1600000
#define NBINS (2 * NN)
#define SCAN_NB ((NBINS + 255) / 256)   // 391

typedef __attribute__((ext_vector_type(8))) short bf16x8;
typedef __attribute__((ext_vector_type(8))) unsigned short u16x8;
typedef __attribute__((ext_vector_type(4))) float f32x4;

__device__ __forceinline__ float bf2f(unsigned short u) {
    union { unsigned int u; float f; } v; v.u = ((unsigned int)u) << 16; return v.f;
}
__device__ __forceinline__ unsigned short f2bf(float f) {
    union { float f; unsigned int u; } v; v.f = f;
    unsigned int x = v.u;
    x += ((x >> 16) & 1u) + 0x7FFFu;   // round-to-nearest-even
    return (unsigned short)(x >> 16);
}
__device__ __forceinline__ float lrelu(float v) { return (v > 0.f) ? v : 0.01f * v; }

// lgkm-only barrier: LDS ops drained, global loads (vmcnt) stay in flight.
#define BAR_LGKM() asm volatile("s_waitcnt lgkmcnt(0)\n\ts_barrier" ::: "memory")

// ------- transpose + hi/lo split: src fp32 [K][128] -> hi/lo bf16 [128][K] -------
__global__ void rg_transpose_split(const float* __restrict__ src,
                                   unsigned short* __restrict__ dhi,
                                   unsigned short* __restrict__ dlo,
                                   int total, int K) {
    int i = blockIdx.x * 256 + threadIdx.x;
    if (i >= total) return;
    int k = i >> 7;
    int c = i & 127;
    float v = src[i];
    unsigned short h = f2bf(v);
    dhi[c * K + k] = h;
    dlo[c * K + k] = f2bf(v - bf2f(h));
}

// ---------------- edge counting sort (once per call, reused by both layers) ----------------
__global__ void rg_hist(const int* __restrict__ ei, const int* __restrict__ et,
                        int* __restrict__ hist) {
    int e = blockIdx.x * 256 + threadIdx.x;
    if (e >= EE) return;
    const int dst = ei[EE + e];
    const int r = et[e];
    atomicAdd(&hist[r * NN + dst], 1);
}

// ---- 3-phase parallel exclusive scan over NBINS bins (coalesced, multi-CU) ----
__global__ void rg_scan_blk(const int* __restrict__ hist, int* __restrict__ bsum) {
    const int t = threadIdx.x;
    const int idx = blockIdx.x * 256 + t;
    int v = (idx < NBINS) ? hist[idx] : 0;
#pragma unroll
    for (int off = 32; off > 0; off >>= 1) v += __shfl_down(v, off, 64);
    __shared__ int ws[4];
    if ((t & 63) == 0) ws[t >> 6] = v;
    __syncthreads();
    if (t == 0) bsum[blockIdx.x] = ws[0] + ws[1] + ws[2] + ws[3];
}

__global__ void rg_scan_top(const int* __restrict__ bsum, int* __restrict__ boff,
                            int* __restrict__ offs) {
    __shared__ int ls[512];
    const int t = threadIdx.x;
    const int v = (t < SCAN_NB) ? bsum[t] : 0;
    ls[t] = v;
    __syncthreads();
    for (int d = 1; d < 512; d <<= 1) {
        const int u = (t >= d) ? ls[t - d] : 0;
        __syncthreads();
        ls[t] += u;
        __syncthreads();
    }
    if (t < SCAN_NB) boff[t] = ls[t] - v;        // exclusive
    if (t == SCAN_NB - 1) offs[NBINS] = ls[t];   // total == EE
}

__global__ void rg_scan_fin(const int* __restrict__ hist, const int* __restrict__ boff,
                            int* __restrict__ offs) {
    __shared__ int ls[256];
    const int t = threadIdx.x;
    const int idx = blockIdx.x * 256 + t;
    const int v = (idx < NBINS) ? hist[idx] : 0;
    ls[t] = v;
    __syncthreads();
    for (int d = 1; d < 256; d <<= 1) {
        const int u = (t >= d) ? ls[t - d] : 0;
        __syncthreads();
        ls[t] += u;
        __syncthreads();
    }
    if (idx < NBINS) offs[idx] = boff[blockIdx.x] + ls[t] - v;   // exclusive
}

__global__ void rg_place(const int* __restrict__ ei, const int* __restrict__ et,
                         int* __restrict__ cursor, int* __restrict__ sorted_src) {
    int e = blockIdx.x * 256 + threadIdx.x;
    if (e >= EE) return;
    const int src = ei[e];
    const int dst = ei[EE + e];
    const int r = et[e];
    const int pos = atomicAdd(&cursor[r * NN + dst], 1);
    sorted_src[pos] = src;
}

// ------- atomic-free gather-reduce: agg[bin][:] = mean over sorted src rows -------
__global__ void rg_gather(const float* __restrict__ xf,
                          const int* __restrict__ sorted_src,
                          const int* __restrict__ offs,
                          float* __restrict__ agg) {
    const int lane = threadIdx.x & 63;
    const int gw = (blockIdx.x * blockDim.x + threadIdx.x) >> 6;
    const int nw = (gridDim.x * blockDim.x) >> 6;
    for (int bin = gw; bin < NBINS; bin += nw) {
        const int s = offs[bin], e = offs[bin + 1];
        float ax = 0.f, ay = 0.f;
        int i = s;
        for (; i + 3 < e; i += 4) {                 // 4 row loads in flight
            const int s0 = sorted_src[i];
            const int s1 = sorted_src[i + 1];
            const int s2 = sorted_src[i + 2];
            const int s3 = sorted_src[i + 3];
            const float2 v0 = *(const float2*)(xf + (long)s0 * 128 + lane * 2);
            const float2 v1 = *(const float2*)(xf + (long)s1 * 128 + lane * 2);
            const float2 v2 = *(const float2*)(xf + (long)s2 * 128 + lane * 2);
            const float2 v3 = *(const float2*)(xf + (long)s3 * 128 + lane * 2);
            ax += (v0.x + v1.x) + (v2.x + v3.x);
            ay += (v0.y + v1.y) + (v2.y + v3.y);
        }
        for (; i < e; ++i) {
            const int s0 = sorted_src[i];
            const float2 v0 = *(const float2*)(xf + (long)s0 * 128 + lane * 2);
            ax += v0.x;
            ay += v0.y;
        }
        const float c = fmaxf((float)(e - s), 1.0f);
        *(float2*)(agg + (long)bin * 128 + lane * 2) = make_float2(ax / c, ay / c);
    }
}

// ------- unified MFMA GEMM: A-direct fragment loads, B-only LDS -------
// grid = njobs * bps. Per job: up to 3 (A,B) ops accumulated into one output.
// A rows have zero cross-wave reuse -> load A fragments straight from global
// (coalesced at 128B-line granularity), prefetched one K-step ahead across
// lgkm-only barriers (A vmcnt stays in flight through both barriers).
// B (shared by all 4 waves) staged per 32-k chunk in LDS (20 KB -> 8 blocks/CU).
struct MMArgs {
    const float* A[9];            // [job*3+op]
    const unsigned short* BH[9];
    const unsigned short* BL[9];
    int kbase[9];
    float* O[3];                  // per job
    const float* bias[3];
    int nops[3];
    int ksteps[3];                // per-op ksteps (uniform within job)
    int Kstr[3];
    int act[3];                   // 0=raw partial, 1=bias+lrelu, 2=bias+relu
};

__global__ __launch_bounds__(256) void rg_mm(MMArgs g, int bps)
{
    __shared__ unsigned short Bhi[128 * 40];
    __shared__ unsigned short Blo[128 * 40];

    const int job = blockIdx.x / bps;
    const int blk = blockIdx.x - job * bps;
    const int tid = threadIdx.x;
    const int wave = tid >> 6, lane = tid & 63, q = lane >> 4, m15 = lane & 15;
    const int row0 = blk * 64;
    const int Kstr = g.Kstr[job];
    const int nops = g.nops[job];
    const int ksteps = g.ksteps[job];

    const int arow = row0 + wave * 16 + m15;
    const int rowc = (arow < NN) ? arow : (NN - 1);    // clamped: garbage rows -> discarded outputs
    const long rowoff = (long)rowc * Kstr + q * 8;

    const int bn = tid >> 1, bhalf = (tid & 1) * 16;

    f32x4 acc[8];
#pragma unroll
    for (int t = 0; t < 8; ++t) acc[t] = (f32x4){0.f, 0.f, 0.f, 0.f};

    // prologue A prefetch: (op0, ks0)
    const float* Ap0 = g.A[job * 3] + rowoff + g.kbase[job * 3];
    f32x4 va0 = *(const f32x4*)(Ap0);
    f32x4 va1 = *(const f32x4*)(Ap0 + 4);

    for (int op = 0; op < nops; ++op) {
        const unsigned short* BH = g.BH[job * 3 + op];
        const unsigned short* BL = g.BL[job * 3 + op];
        const int kb = g.kbase[job * 3 + op];
        for (int ks = 0; ks < ksteps; ++ks) {
            const int k0 = kb + (ks << 5);
            // WAR: everyone done reading previous B chunk (lgkm only; A loads fly on)
            BAR_LGKM();
            // B chunk loads (tiny, L2-hot)
            const long bo = (long)bn * Kstr + k0 + bhalf;
            const u16x8 h0 = *(const u16x8*)(BH + bo);
            const u16x8 h1 = *(const u16x8*)(BH + bo + 8);
            const u16x8 l0 = *(const u16x8*)(BL + bo);
            const u16x8 l1 = *(const u16x8*)(BL + bo + 8);
            // A prefetch for next step (HBM latency spans both barriers + MFMA)
            int nop = op, nks = ks + 1;
            if (nks == ksteps) { nks = 0; if (op + 1 < nops) nop = op + 1; }
            const float* An = g.A[job * 3 + nop] + rowoff + g.kbase[job * 3 + nop] + (nks << 5);
            const f32x4 vn0 = *(const f32x4*)(An);
            const f32x4 vn1 = *(const f32x4*)(An + 4);
            // publish B
            *(u16x8*)(Bhi + bn * 40 + bhalf)     = h0;
            *(u16x8*)(Bhi + bn * 40 + bhalf + 8) = h1;
            *(u16x8*)(Blo + bn * 40 + bhalf)     = l0;
            *(u16x8*)(Blo + bn * 40 + bhalf + 8) = l1;
            // RAW: B chunk visible to all waves
            BAR_LGKM();
            // convert current A regs -> hi/lo fragments
            u16x8 uh, ul;
#pragma unroll
            for (int j = 0; j < 4; ++j) {
                const unsigned short hh0 = f2bf(va0[j]);
                uh[j] = hh0;  ul[j] = f2bf(va0[j] - bf2f(hh0));
                const unsigned short hh1 = f2bf(va1[j]);
                uh[j + 4] = hh1;  ul[j + 4] = f2bf(va1[j] - bf2f(hh1));
            }
            const bf16x8 ah = *(const bf16x8*)&uh;
            const bf16x8 al = *(const bf16x8*)&ul;
#pragma unroll
            for (int t = 0; t < 8; ++t) {
                const bf16x8 bh = *(const bf16x8*)(Bhi + ((t << 4) + m15) * 40 + q * 8);
                const bf16x8 bl = *(const bf16x8*)(Blo + ((t << 4) + m15) * 40 + q * 8);
                acc[t] = __builtin_amdgcn_mfma_f32_16x16x32_bf16(ah, bh, acc[t], 0, 0, 0);
                acc[t] = __builtin_amdgcn_mfma_f32_16x16x32_bf16(al, bh, acc[t], 0, 0, 0);
                acc[t] = __builtin_amdgcn_mfma_f32_16x16x32_bf16(ah, bl, acc[t], 0, 0, 0);
            }
            va0 = vn0;
            va1 = vn1;
        }
    }

    float* O = g.O[job];
    const float* bias = g.bias[job];
    const int act = g.act[job];
#pragma unroll
    for (int t = 0; t < 8; ++t) {
        const int col = (t << 4) + m15;
        const float bv = (act != 0) ? bias[col] : 0.f;
#pragma unroll
        for (int i = 0; i < 4; ++i) {
            const int r = row0 + wave * 16 + q * 4 + i;
            if (r < NN) {
                float v = acc[t][i] + bv;
                if (act == 1) v = lrelu(v);
                else if (act == 2) v = fmaxf(v, 0.f);
                O[(long)r * 128 + col] = v;
            }
        }
    }
}

// ------- proj finisher: xf = lrelu(twe)+lrelu(des)+lrelu(num)+lrelu(cat) -------
__global__ void rg_proj_fin(
    const float* __restrict__ Ptwe,
    const float* __restrict__ Pd0, const float* __restrict__ Pd1,
    const float* __restrict__ numf, const float* __restrict__ catf,
    const float* __restrict__ num_w, const float* __restrict__ cat_w,
    const float* __restrict__ desB, const float* __restrict__ tweB,
    const float* __restrict__ numB, const float* __restrict__ catB,
    float* __restrict__ xf)
{
    const int lane = threadIdx.x & 63;
    const int gw = (blockIdx.x * blockDim.x + threadIdx.x) >> 6;
    const int nw = (gridDim.x * blockDim.x) >> 6;
    const int c = lane * 2;

    float wn0[5], wn1[5], wc0[6], wc1[6];
#pragma unroll
    for (int k = 0; k < 5; ++k) { wn0[k] = num_w[k * 128 + c]; wn1[k] = num_w[k * 128 + c + 1]; }
#pragma unroll
    for (int k = 0; k < 6; ++k) { wc0[k] = cat_w[k * 128 + c]; wc1[k] = cat_w[k * 128 + c + 1]; }
    const float bn0 = numB[c], bn1 = numB[c + 1];
    const float bc0 = catB[c], bc1 = catB[c + 1];
    const float bd0 = desB[c], bd1 = desB[c + 1];
    const float bt0 = tweB[c], bt1 = tweB[c + 1];

    for (int n = gw; n < NN; n += nw) {
        const long o = (long)n * 128 + c;
        const float2 tw = *(const float2*)(Ptwe + o);
        const float2 d0 = *(const float2*)(Pd0 + o);
        const float2 d1 = *(const float2*)(Pd1 + o);
        float nv[5], cv[6];
#pragma unroll
        for (int k = 0; k < 5; ++k) nv[k] = numf[(long)n * 5 + k];
#pragma unroll
        for (int k = 0; k < 6; ++k) cv[k] = catf[(long)n * 6 + k];
        float s1x = bn0, s1y = bn1;
#pragma unroll
        for (int k = 0; k < 5; ++k) { s1x += nv[k] * wn0[k]; s1y += nv[k] * wn1[k]; }
        float s2x = bc0, s2y = bc1;
#pragma unroll
        for (int k = 0; k < 6; ++k) { s2x += cv[k] * wc0[k]; s2y += cv[k] * wc1[k]; }
        const float rx = lrelu(tw.x + bt0) + lrelu(d0.x + d1.x + bd0)
                       + lrelu(s1x) + lrelu(s2x);
        const float ry = lrelu(tw.y + bt1) + lrelu(d0.y + d1.y + bd1)
                       + lrelu(s1y) + lrelu(s2y);
        *(float2*)(xf + o) = make_float2(rx, ry);
    }
}

// ---------------- final 128->2 head ----------------
__global__ void BotRGCN_64381559767213_kernel(const float* __restrict__ hf,
                                              const float* __restrict__ w2,
                                              const float* __restrict__ b2,
                                              float* __restrict__ out)
{
    const int lane = threadIdx.x & 63;
    const int gw = (blockIdx.x * blockDim.x + threadIdx.x) >> 6;
    const int nw = (gridDim.x * blockDim.x) >> 6;
    const int k2 = lane * 2;
    const float w00 = w2[k2 * 2 + 0], w01 = w2[k2 * 2 + 1];
    const float w10 = w2[k2 * 2 + 2], w11 = w2[k2 * 2 + 3];
    const float b0 = b2[0], b1 = b2[1];
    for (int n = gw; n < NN; n += nw) {
        const float2 v = *(const float2*)(hf + (long)n * 128 + k2);
        float p0 = v.x * w00 + v.y * w10;
        float p1 = v.x * w01 + v.y * w11;
#pragma unroll
        for (int off = 32; off > 0; off >>= 1) {
            p0 += __shfl_down(p0, off, 64);
            p1 += __shfl_down(p1, off, 64);
        }
        if (lane == 0) {
            *(float2*)(out + (long)n * 2) = make_float2(p0 + b0, p1 + b1);
        }
    }
}

extern "C" void kernel_launch(void* const* d_in, const int* in_sizes, int n_in,
                              void* d_out, int out_size, void* d_ws, size_t ws_size,
                              hipStream_t stream)
{
    const float* des    = (const float*)d_in[0];
    const float* twe    = (const float*)d_in[1];
    const float* num    = (const float*)d_in[2];
    const float* cat    = (const float*)d_in[3];
    const int*   ei     = (const int*)d_in[4];
    const int*   et     = (const int*)d_in[5];
    const float* des_w  = (const float*)d_in[6];
    const float* des_b  = (const float*)d_in[7];
    const float* twe_w  = (const float*)d_in[8];
    const float* twe_b  = (const float*)d_in[9];
    const float* num_w  = (const float*)d_in[10];
    const float* num_b  = (const float*)d_in[11];
    const float* cat_w  = (const float*)d_in[12];
    const float* cat_b  = (const float*)d_in[13];
    const float* rel_w  = (const float*)d_in[14];
    const float* root_w = (const float*)d_in[15];
    const float* rgcn_b = (const float*)d_in[16];
    const float* mlp_w1 = (const float*)d_in[17];
    const float* mlp_b1 = (const float*)d_in[18];
    const float* mlp_w2 = (const float*)d_in[19];
    const float* mlp_b2 = (const float*)d_in[20];

    char* ws = (char*)d_ws;
    size_t off = 0;
    auto alloc = [&](size_t bytes) -> char* {
        char* p = ws + off;
        off += (bytes + 255) & ~(size_t)255;
        return p;
    };
    float* xf  = (float*)alloc((size_t)NN * 128 * 4);        // 25.6 MB
    float* agg = (float*)alloc((size_t)NBINS * 128 * 4);     // 51.2 MB
    int* hist       = (int*)alloc((size_t)NBINS * 4);
    int* offs       = (int*)alloc((size_t)(NBINS + 1) * 4);
    int* cursor     = (int*)alloc((size_t)NBINS * 4);
    int* sorted_src = (int*)alloc((size_t)EE * 4);           // 6.4 MB
    int* bsum       = (int*)alloc((size_t)SCAN_NB * 4);
    int* boff       = (int*)alloc((size_t)SCAN_NB * 4);
    unsigned short* desHi = (unsigned short*)alloc((size_t)768 * 128 * 2);
    unsigned short* desLo = (unsigned short*)alloc((size_t)768 * 128 * 2);
    unsigned short* tweHi = (unsigned short*)alloc((size_t)768 * 128 * 2);
    unsigned short* tweLo = (unsigned short*)alloc((size_t)768 * 128 * 2);
    unsigned short* rootHi = (unsigned short*)alloc((size_t)2 * 16384 * 2);
    unsigned short* rootLo = (unsigned short*)alloc((size_t)2 * 16384 * 2);
    unsigned short* relHi  = (unsigned short*)alloc((size_t)4 * 16384 * 2);
    unsigned short* relLo  = (unsigned short*)alloc((size_t)4 * 16384 * 2);
    unsigned short* w1Hi   = (unsigned short*)alloc((size_t)16384 * 2);
    unsigned short* w1Lo   = (unsigned short*)alloc((size_t)16384 * 2);
    float* hf = agg;   // agg is dead once the MLP runs

    // ---- weight prep (tiny) ----
    auto tr = [&](const float* s, unsigned short* dh, unsigned short* dl, int K) {
        const int total = K * 128;
        rg_transpose_split<<<(total + 255) / 256, 256, 0, stream>>>(s, dh, dl, total, K);
    };
    tr(des_w, desHi, desLo, 768);
    tr(twe_w, tweHi, tweLo, 768);
    tr(root_w,         rootHi,         rootLo,         128);
    tr(root_w + 16384, rootHi + 16384, rootLo + 16384, 128);
    tr(rel_w + 0 * 16384, relHi + 0 * 16384, relLo + 0 * 16384, 128);
    tr(rel_w + 1 * 16384, relHi + 1 * 16384, relLo + 1 * 16384, 128);
    tr(rel_w + 2 * 16384, relHi + 2 * 16384, relLo + 2 * 16384, 128);
    tr(rel_w + 3 * 16384, relHi + 3 * 16384, relLo + 3 * 16384, 128);
    tr(mlp_w1, w1Hi, w1Lo, 128);

    // ---- edge sort (once; reused by both layers) ----
    hipMemsetAsync(hist, 0, (size_t)NBINS * 4, stream);
    rg_hist<<<(EE + 255) / 256, 256, 0, stream>>>(ei, et, hist);
    rg_scan_blk<<<SCAN_NB, 256, 0, stream>>>(hist, bsum);
    rg_scan_top<<<1, 512, 0, stream>>>(bsum, boff, offs);
    rg_scan_fin<<<SCAN_NB, 256, 0, stream>>>(hist, boff, offs);
    hipMemcpyAsync(cursor, offs, (size_t)NBINS * 4, hipMemcpyDeviceToDevice, stream);
    rg_place<<<(EE + 255) / 256, 256, 0, stream>>>(ei, et, cursor, sorted_src);

    const int bps = (NN + 63) / 64;  // 782

    // ---- projection: 3 jobs {twe full-K -> xf, des K-halves -> agg halves} ----
    {
        MMArgs a = {};
        // job0: twe, full K
        a.A[0] = twe;  a.BH[0] = tweHi; a.BL[0] = tweLo; a.kbase[0] = 0;
        a.O[0] = xf;   a.bias[0] = nullptr; a.nops[0] = 1; a.ksteps[0] = 24;
        a.Kstr[0] = 768; a.act[0] = 0;
        // job1: des, k 0..383
        a.A[3] = des;  a.BH[3] = desHi; a.BL[3] = desLo; a.kbase[3] = 0;
        a.O[1] = agg;  a.bias[1] = nullptr; a.nops[1] = 1; a.ksteps[1] = 12;
        a.Kstr[1] = 768; a.act[1] = 0;
        // job2: des, k 384..767
        a.A[6] = des;  a.BH[6] = desHi; a.BL[6] = desLo; a.kbase[6] = 384;
        a.O[2] = agg + (size_t)NN * 128; a.bias[2] = nullptr; a.nops[2] = 1;
        a.ksteps[2] = 12; a.Kstr[2] = 768; a.act[2] = 0;
        rg_mm<<<3 * bps, 256, 0, stream>>>(a, bps);
    }
    rg_proj_fin<<<2048, 256, 0, stream>>>(xf, agg, agg + (size_t)NN * 128,
                                          num, cat, num_w, cat_w,
                                          des_b, twe_b, num_b, cat_b, xf);

    // ---- RGCN layers: gather-reduce + 3-op accumulated GEMM (bias+lrelu fused) ----
    const int gather_grid = (NBINS * 64 + 255) / 256;
    for (int l = 0; l < 2; ++l) {
        rg_gather<<<gather_grid, 256, 0, stream>>>(xf, sorted_src, offs, agg);
        MMArgs a = {};
        a.A[0] = xf;                       a.BH[0] = rootHi + (size_t)l * 16384;
        a.BL[0] = rootLo + (size_t)l * 16384;          a.kbase[0] = 0;
        a.A[1] = agg;                      a.BH[1] = relHi + (size_t)(l * 2) * 16384;
        a.BL[1] = relLo + (size_t)(l * 2) * 16384;     a.kbase[1] = 0;
        a.A[2] = agg + (size_t)NN * 128;   a.BH[2] = relHi + (size_t)(l * 2 + 1) * 16384;
        a.BL[2] = relLo + (size_t)(l * 2 + 1) * 16384; a.kbase[2] = 0;
        a.O[0] = xf; a.bias[0] = rgcn_b + l * 128;
        a.nops[0] = 3; a.ksteps[0] = 4; a.Kstr[0] = 128; a.act[0] = 1;
        rg_mm<<<bps, 256, 0, stream>>>(a, bps);
    }

    // ---- MLP layer 1 (relu) ----
    {
        MMArgs a = {};
        a.A[0] = xf; a.BH[0] = w1Hi; a.BL[0] = w1Lo; a.kbase[0] = 0;
        a.O[0] = hf; a.bias[0] = mlp_b1;
        a.nops[0] = 1; a.ksteps[0] = 4; a.Kstr[0] = 128; a.act[0] = 2;
        rg_mm<<<bps, 256, 0, stream>>>(a, bps);
    }

    // ---- head ----
    BotRGCN_64381559767213_kernel<<<2048, 256, 0, stream>>>(hf, mlp_w2, mlp_b2,
                                                            (float*)d_out);
}

// Round 6
// 914.840 us; speedup vs baseline: 1.0739x; 1.0739x over previous
//
#include <hip/hip_runtime.h>

#define NN 50000
#define EE 1600000
#define NBINS (2 * NN)
#define SCAN_NB ((NBINS + 255) / 256)   // 391

typedef __attribute__((ext_vector_type(8))) short bf16x8;
typedef __attribute__((ext_vector_type(8))) unsigned short u16x8;
typedef __attribute__((ext_vector_type(4))) float f32x4;

__device__ __forceinline__ float bf2f(unsigned short u) {
    union { unsigned int u; float f; } v; v.u = ((unsigned int)u) << 16; return v.f;
}
__device__ __forceinline__ unsigned short f2bf(float f) {
    union { float f; unsigned int u; } v; v.f = f;
    unsigned int x = v.u;
    x += ((x >> 16) & 1u) + 0x7FFFu;   // round-to-nearest-even
    return (unsigned short)(x >> 16);
}
__device__ __forceinline__ float lrelu(float v) { return (v > 0.f) ? v : 0.01f * v; }

// ------- fused transpose + hi/lo split for ALL weight matrices (one launch) -------
// Each segment: src fp32 [K][128] -> dhi/dlo bf16 [128][K].
struct TRArgs {
    const float* src[9];
    unsigned short* dhi[9];
    unsigned short* dlo[9];
    int K[9];
    int base[10];   // prefix of K*128
};

__global__ void rg_tr_all(TRArgs a) {
    const int i = blockIdx.x * 256 + threadIdx.x;
    if (i >= a.base[9]) return;
    int s = 0;
    while (s < 8 && i >= a.base[s + 1]) ++s;
    const int j = i - a.base[s];
    const int K = a.K[s];
    const int k = j >> 7;
    const int c = j & 127;
    const float v = a.src[s][j];
    const unsigned short h = f2bf(v);
    a.dhi[s][c * K + k] = h;
    a.dlo[s][c * K + k] = f2bf(v - bf2f(h));
}

// ---------------- edge counting sort (once per call, reused by both layers) ----------------
__global__ void rg_hist(const int* __restrict__ ei, const int* __restrict__ et,
                        int* __restrict__ hist) {
    int e = blockIdx.x * 256 + threadIdx.x;
    if (e >= EE) return;
    const int dst = ei[EE + e];
    const int r = et[e];
    atomicAdd(&hist[r * NN + dst], 1);
}

// ---- 3-phase parallel exclusive scan over NBINS bins (coalesced, multi-CU) ----
__global__ void rg_scan_blk(const int* __restrict__ hist, int* __restrict__ bsum) {
    const int t = threadIdx.x;
    const int idx = blockIdx.x * 256 + t;
    int v = (idx < NBINS) ? hist[idx] : 0;
#pragma unroll
    for (int off = 32; off > 0; off >>= 1) v += __shfl_down(v, off, 64);
    __shared__ int ws[4];
    if ((t & 63) == 0) ws[t >> 6] = v;
    __syncthreads();
    if (t == 0) bsum[blockIdx.x] = ws[0] + ws[1] + ws[2] + ws[3];
}

__global__ void rg_scan_top(const int* __restrict__ bsum, int* __restrict__ boff,
                            int* __restrict__ offs) {
    __shared__ int ls[512];
    const int t = threadIdx.x;
    const int v = (t < SCAN_NB) ? bsum[t] : 0;
    ls[t] = v;
    __syncthreads();
    for (int d = 1; d < 512; d <<= 1) {
        const int u = (t >= d) ? ls[t - d] : 0;
        __syncthreads();
        ls[t] += u;
        __syncthreads();
    }
    if (t < SCAN_NB) boff[t] = ls[t] - v;        // exclusive
    if (t == SCAN_NB - 1) offs[NBINS] = ls[t];   // total == EE
}

// writes BOTH offs and cursor (saves the D2D copy launch)
__global__ void rg_scan_fin(const int* __restrict__ hist, const int* __restrict__ boff,
                            int* __restrict__ offs, int* __restrict__ cursor) {
    __shared__ int ls[256];
    const int t = threadIdx.x;
    const int idx = blockIdx.x * 256 + t;
    const int v = (idx < NBINS) ? hist[idx] : 0;
    ls[t] = v;
    __syncthreads();
    for (int d = 1; d < 256; d <<= 1) {
        const int u = (t >= d) ? ls[t - d] : 0;
        __syncthreads();
        ls[t] += u;
        __syncthreads();
    }
    if (idx < NBINS) {
        const int o = boff[blockIdx.x] + ls[t] - v;   // exclusive
        offs[idx] = o;
        cursor[idx] = o;
    }
}

__global__ void rg_place(const int* __restrict__ ei, const int* __restrict__ et,
                         int* __restrict__ cursor, int* __restrict__ sorted_src) {
    int e = blockIdx.x * 256 + threadIdx.x;
    if (e >= EE) return;
    const int src = ei[e];
    const int dst = ei[EE + e];
    const int r = et[e];
    const int pos = atomicAdd(&cursor[r * NN + dst], 1);
    sorted_src[pos] = src;
}

// ------- atomic-free gather-reduce: agg[bin][:] = mean over sorted src rows -------
// 2 rows per wave (half-wave x float4/lane), x2 unroll = 4 row loads in flight.
__global__ void rg_gather(const float* __restrict__ xf,
                          const int* __restrict__ sorted_src,
                          const int* __restrict__ offs,
                          float* __restrict__ agg) {
    const int lane = threadIdx.x & 63;
    const int half = lane >> 5;        // 0: rows i, i+2 ; 1: rows i+1, i+3
    const int l32 = lane & 31;
    const int gw = (blockIdx.x * blockDim.x + threadIdx.x) >> 6;
    const int nw = (gridDim.x * blockDim.x) >> 6;
    for (int bin = gw; bin < NBINS; bin += nw) {
        const int s = offs[bin], e = offs[bin + 1];
        f32x4 a0 = (f32x4){0.f, 0.f, 0.f, 0.f};
        f32x4 a1 = (f32x4){0.f, 0.f, 0.f, 0.f};
        int i = s;
        for (; i + 3 < e; i += 4) {
            const int r0 = sorted_src[i + half];
            const int r1 = sorted_src[i + 2 + half];
            const f32x4 v0 = *(const f32x4*)(xf + (long)r0 * 128 + l32 * 4);
            const f32x4 v1 = *(const f32x4*)(xf + (long)r1 * 128 + l32 * 4);
            a0 += v0;
            a1 += v1;
        }
        for (; i < e; i += 2) {
            const int idx = i + half;
            if (idx < e) {
                const int r0 = sorted_src[idx];
                a0 += *(const f32x4*)(xf + (long)r0 * 128 + l32 * 4);
            }
        }
        a0 += a1;
#pragma unroll
        for (int j = 0; j < 4; ++j) a0[j] += __shfl_xor(a0[j], 32, 64);
        if (half == 0) {
            const float c = fmaxf((float)(e - s), 1.0f);
            f32x4 o;
#pragma unroll
            for (int j = 0; j < 4; ++j) o[j] = a0[j] / c;
            *(f32x4*)(agg + (long)bin * 128 + l32 * 4) = o;
        }
    }
}

// ------- generic partial GEMM (r4-proven): per-segment (A, B, K-chunk) -> fp32 partial -------
__global__ __launch_bounds__(256) void rg_part(
    const float* __restrict__ A0, const float* __restrict__ A1,
    const float* __restrict__ A2,
    const unsigned short* __restrict__ BH0, const unsigned short* __restrict__ BH1,
    const unsigned short* __restrict__ BH2,
    const unsigned short* __restrict__ BL0, const unsigned short* __restrict__ BL1,
    const unsigned short* __restrict__ BL2,
    float* __restrict__ O0, float* __restrict__ O1, float* __restrict__ O2,
    int kb0, int kb1, int kb2,
    int ks0, int ks1, int ks2,
    int Kstr, int bps)
{
    __shared__ unsigned short Ahi[64 * 40];
    __shared__ unsigned short Alo[64 * 40];
    __shared__ unsigned short Bhi[128 * 40];
    __shared__ unsigned short Blo[128 * 40];

    const int seg = blockIdx.x / bps;
    const int blk = blockIdx.x - seg * bps;

    const float* A;
    const unsigned short* BH;
    const unsigned short* BL;
    float* O;
    int kbase, ksteps;
    if (seg == 0)      { A = A0; BH = BH0; BL = BL0; O = O0; kbase = kb0; ksteps = ks0; }
    else if (seg == 1) { A = A1; BH = BH1; BL = BL1; O = O1; kbase = kb1; ksteps = ks1; }
    else               { A = A2; BH = BH2; BL = BL2; O = O2; kbase = kb2; ksteps = ks2; }

    const int tid = threadIdx.x;
    const int wave = tid >> 6, lane = tid & 63, q = lane >> 4, m15 = lane & 15;
    const int row0 = blk * 64;
    const int ar = tid >> 2, aseg = tid & 3;
    const int bn = tid >> 1, bb = (tid & 1) * 16;
    const int agr = row0 + ar;
    const bool aval = agr < NN;

    f32x4 acc[8];
#pragma unroll
    for (int t = 0; t < 8; ++t) acc[t] = (f32x4){0.f, 0.f, 0.f, 0.f};

    for (int ks = 0; ks < ksteps; ++ks) {
        const int k0 = kbase + (ks << 5);
        __syncthreads();
        {   // A stage: fp32 load + hi/lo split
            u16x8 hi = {0,0,0,0,0,0,0,0}, lo = {0,0,0,0,0,0,0,0};
            if (aval) {
                const float* p = A + (long)agr * Kstr + k0 + aseg * 8;
                const f32x4 v0 = *(const f32x4*)p;
                const f32x4 v1 = *(const f32x4*)(p + 4);
#pragma unroll
                for (int j = 0; j < 4; ++j) {
                    unsigned short h0 = f2bf(v0[j]);
                    hi[j] = h0;  lo[j] = f2bf(v0[j] - bf2f(h0));
                    unsigned short h1 = f2bf(v1[j]);
                    hi[j+4] = h1; lo[j+4] = f2bf(v1[j] - bf2f(h1));
                }
            }
            *(u16x8*)(Ahi + ar * 40 + aseg * 8) = hi;
            *(u16x8*)(Alo + ar * 40 + aseg * 8) = lo;
        }
        {   // B stage (pre-split bf16, [128][Kstr] row-major)
            const long bo = (long)bn * Kstr + k0 + bb;
            *(u16x8*)(Bhi + bn * 40 + bb)     = *(const u16x8*)(BH + bo);
            *(u16x8*)(Bhi + bn * 40 + bb + 8) = *(const u16x8*)(BH + bo + 8);
            *(u16x8*)(Blo + bn * 40 + bb)     = *(const u16x8*)(BL + bo);
            *(u16x8*)(Blo + bn * 40 + bb + 8) = *(const u16x8*)(BL + bo + 8);
        }
        __syncthreads();
        const bf16x8 ah = *(const bf16x8*)(Ahi + (wave * 16 + m15) * 40 + q * 8);
        const bf16x8 al = *(const bf16x8*)(Alo + (wave * 16 + m15) * 40 + q * 8);
#pragma unroll
        for (int t = 0; t < 8; ++t) {
            const bf16x8 bh = *(const bf16x8*)(Bhi + ((t << 4) + m15) * 40 + q * 8);
            const bf16x8 bl = *(const bf16x8*)(Blo + ((t << 4) + m15) * 40 + q * 8);
            acc[t] = __builtin_amdgcn_mfma_f32_16x16x32_bf16(ah, bh, acc[t], 0, 0, 0);
            acc[t] = __builtin_amdgcn_mfma_f32_16x16x32_bf16(al, bh, acc[t], 0, 0, 0);
            acc[t] = __builtin_amdgcn_mfma_f32_16x16x32_bf16(ah, bl, acc[t], 0, 0, 0);
        }
    }
#pragma unroll
    for (int t = 0; t < 8; ++t) {
        const int col = (t << 4) + m15;
#pragma unroll
        for (int i = 0; i < 4; ++i) {
            const int r = row0 + wave * 16 + q * 4 + i;
            if (r < NN) O[(long)r * 128 + col] = acc[t][i];
        }
    }
}

// ------- proj finisher: xf = lrelu(twe)+lrelu(des)+lrelu(num)+lrelu(cat) -------
__global__ void rg_proj_fin(
    const float* __restrict__ Ptwe,
    const float* __restrict__ Pd0, const float* __restrict__ Pd1,
    const float* __restrict__ numf, const float* __restrict__ catf,
    const float* __restrict__ num_w, const float* __restrict__ cat_w,
    const float* __restrict__ desB, const float* __restrict__ tweB,
    const float* __restrict__ numB, const float* __restrict__ catB,
    float* __restrict__ xf)
{
    const int lane = threadIdx.x & 63;
    const int gw = (blockIdx.x * blockDim.x + threadIdx.x) >> 6;
    const int nw = (gridDim.x * blockDim.x) >> 6;
    const int c = lane * 2;

    float wn0[5], wn1[5], wc0[6], wc1[6];
#pragma unroll
    for (int k = 0; k < 5; ++k) { wn0[k] = num_w[k * 128 + c]; wn1[k] = num_w[k * 128 + c + 1]; }
#pragma unroll
    for (int k = 0; k < 6; ++k) { wc0[k] = cat_w[k * 128 + c]; wc1[k] = cat_w[k * 128 + c + 1]; }
    const float bn0 = numB[c], bn1 = numB[c + 1];
    const float bc0 = catB[c], bc1 = catB[c + 1];
    const float bd0 = desB[c], bd1 = desB[c + 1];
    const float bt0 = tweB[c], bt1 = tweB[c + 1];

    for (int n = gw; n < NN; n += nw) {
        const long o = (long)n * 128 + c;
        const float2 tw = *(const float2*)(Ptwe + o);
        const float2 d0 = *(const float2*)(Pd0 + o);
        const float2 d1 = *(const float2*)(Pd1 + o);
        float nv[5], cv[6];
#pragma unroll
        for (int k = 0; k < 5; ++k) nv[k] = numf[(long)n * 5 + k];
#pragma unroll
        for (int k = 0; k < 6; ++k) cv[k] = catf[(long)n * 6 + k];
        float s1x = bn0, s1y = bn1;
#pragma unroll
        for (int k = 0; k < 5; ++k) { s1x += nv[k] * wn0[k]; s1y += nv[k] * wn1[k]; }
        float s2x = bc0, s2y = bc1;
#pragma unroll
        for (int k = 0; k < 6; ++k) { s2x += cv[k] * wc0[k]; s2y += cv[k] * wc1[k]; }
        const float rx = lrelu(tw.x + bt0) + lrelu(d0.x + d1.x + bd0)
                       + lrelu(s1x) + lrelu(s2x);
        const float ry = lrelu(tw.y + bt1) + lrelu(d0.y + d1.y + bd1)
                       + lrelu(s1y) + lrelu(s2y);
        *(float2*)(xf + o) = make_float2(rx, ry);
    }
}

// ------- fused multi-operand GEMM (r0/r4-proven: loads inside barriers) -------
__global__ __launch_bounds__(256) void rg_gemm(
    const float* __restrict__ A0, const float* __restrict__ A1,
    const float* __restrict__ A2,
    const unsigned short* __restrict__ B0h, const unsigned short* __restrict__ B0l,
    const unsigned short* __restrict__ B1h, const unsigned short* __restrict__ B1l,
    const unsigned short* __restrict__ B2h, const unsigned short* __restrict__ B2l,
    const float* __restrict__ bias, int S, int act,
    float* __restrict__ outf)
{
    __shared__ unsigned short Ahi[64 * 40];
    __shared__ unsigned short Alo[64 * 40];
    __shared__ unsigned short Bhi[128 * 40];
    __shared__ unsigned short Blo[128 * 40];

    const int tid = threadIdx.x;
    const int wave = tid >> 6, lane = tid & 63, q = lane >> 4, m15 = lane & 15;
    const int row0 = blockIdx.x * 64;

    const float* Aptr[3] = { A0, A1, A2 };
    const unsigned short* BHptr[3] = { B0h, B1h, B2h };
    const unsigned short* BLptr[3] = { B0l, B1l, B2l };

    f32x4 acc[8];
#pragma unroll
    for (int t = 0; t < 8; ++t) acc[t] = (f32x4){0.f, 0.f, 0.f, 0.f};

    for (int s = 0; s < S; ++s) {
        const float* A = Aptr[s];
        const unsigned short* BH = BHptr[s];
        const unsigned short* BL = BLptr[s];
#pragma unroll
        for (int ks = 0; ks < 4; ++ks) {
            const int k0 = ks << 5;
            __syncthreads();
            {
                const int r = tid >> 2, seg = tid & 3;
                const int gr = row0 + r;
                u16x8 hi = {0,0,0,0,0,0,0,0}, lo = {0,0,0,0,0,0,0,0};
                if (gr < NN) {
                    const float* p = A + (long)gr * 128 + k0 + seg * 8;
                    const f32x4 v0 = *(const f32x4*)p;
                    const f32x4 v1 = *(const f32x4*)(p + 4);
#pragma unroll
                    for (int j = 0; j < 4; ++j) {
                        unsigned short h0 = f2bf(v0[j]);
                        hi[j] = h0;  lo[j] = f2bf(v0[j] - bf2f(h0));
                        unsigned short h1 = f2bf(v1[j]);
                        hi[j+4] = h1; lo[j+4] = f2bf(v1[j] - bf2f(h1));
                    }
                }
                *(u16x8*)(Ahi + r * 40 + seg * 8) = hi;
                *(u16x8*)(Alo + r * 40 + seg * 8) = lo;
            }
            {
                const int n = tid >> 1;
                const int base = (tid & 1) * 16;
                *(u16x8*)(Bhi + n * 40 + base)     = *(const u16x8*)(BH + (long)n * 128 + k0 + base);
                *(u16x8*)(Bhi + n * 40 + base + 8) = *(const u16x8*)(BH + (long)n * 128 + k0 + base + 8);
                *(u16x8*)(Blo + n * 40 + base)     = *(const u16x8*)(BL + (long)n * 128 + k0 + base);
                *(u16x8*)(Blo + n * 40 + base + 8) = *(const u16x8*)(BL + (long)n * 128 + k0 + base + 8);
            }
            __syncthreads();
            const bf16x8 ah = *(const bf16x8*)(Ahi + (wave * 16 + m15) * 40 + q * 8);
            const bf16x8 al = *(const bf16x8*)(Alo + (wave * 16 + m15) * 40 + q * 8);
#pragma unroll
            for (int t = 0; t < 8; ++t) {
                const bf16x8 bh = *(const bf16x8*)(Bhi + ((t << 4) + m15) * 40 + q * 8);
                const bf16x8 bl = *(const bf16x8*)(Blo + ((t << 4) + m15) * 40 + q * 8);
                acc[t] = __builtin_amdgcn_mfma_f32_16x16x32_bf16(ah, bh, acc[t], 0, 0, 0);
                acc[t] = __builtin_amdgcn_mfma_f32_16x16x32_bf16(al, bh, acc[t], 0, 0, 0);
                acc[t] = __builtin_amdgcn_mfma_f32_16x16x32_bf16(ah, bl, acc[t], 0, 0, 0);
            }
        }
    }
#pragma unroll
    for (int t = 0; t < 8; ++t) {
        const int col = (t << 4) + m15;
        const float bv = bias[col];
#pragma unroll
        for (int i = 0; i < 4; ++i) {
            const int r = row0 + wave * 16 + q * 4 + i;
            if (r < NN) {
                float v = acc[t][i] + bv;
                v = act ? fmaxf(v, 0.f) : ((v > 0.f) ? v : 0.01f * v);
                outf[(long)r * 128 + col] = v;
            }
        }
    }
}

// ---------------- final 128->2 head ----------------
__global__ void BotRGCN_64381559767213_kernel(const float* __restrict__ hf,
                                              const float* __restrict__ w2,
                                              const float* __restrict__ b2,
                                              float* __restrict__ out)
{
    const int lane = threadIdx.x & 63;
    const int gw = (blockIdx.x * blockDim.x + threadIdx.x) >> 6;
    const int nw = (gridDim.x * blockDim.x) >> 6;
    const int k2 = lane * 2;
    const float w00 = w2[k2 * 2 + 0], w01 = w2[k2 * 2 + 1];
    const float w10 = w2[k2 * 2 + 2], w11 = w2[k2 * 2 + 3];
    const float b0 = b2[0], b1 = b2[1];
    for (int n = gw; n < NN; n += nw) {
        const float2 v = *(const float2*)(hf + (long)n * 128 + k2);
        float p0 = v.x * w00 + v.y * w10;
        float p1 = v.x * w01 + v.y * w11;
#pragma unroll
        for (int off = 32; off > 0; off >>= 1) {
            p0 += __shfl_down(p0, off, 64);
            p1 += __shfl_down(p1, off, 64);
        }
        if (lane == 0) {
            *(float2*)(out + (long)n * 2) = make_float2(p0 + b0, p1 + b1);
        }
    }
}

extern "C" void kernel_launch(void* const* d_in, const int* in_sizes, int n_in,
                              void* d_out, int out_size, void* d_ws, size_t ws_size,
                              hipStream_t stream)
{
    const float* des    = (const float*)d_in[0];
    const float* twe    = (const float*)d_in[1];
    const float* num    = (const float*)d_in[2];
    const float* cat    = (const float*)d_in[3];
    const int*   ei     = (const int*)d_in[4];
    const int*   et     = (const int*)d_in[5];
    const float* des_w  = (const float*)d_in[6];
    const float* des_b  = (const float*)d_in[7];
    const float* twe_w  = (const float*)d_in[8];
    const float* twe_b  = (const float*)d_in[9];
    const float* num_w  = (const float*)d_in[10];
    const float* num_b  = (const float*)d_in[11];
    const float* cat_w  = (const float*)d_in[12];
    const float* cat_b  = (const float*)d_in[13];
    const float* rel_w  = (const float*)d_in[14];
    const float* root_w = (const float*)d_in[15];
    const float* rgcn_b = (const float*)d_in[16];
    const float* mlp_w1 = (const float*)d_in[17];
    const float* mlp_b1 = (const float*)d_in[18];
    const float* mlp_w2 = (const float*)d_in[19];
    const float* mlp_b2 = (const float*)d_in[20];

    char* ws = (char*)d_ws;
    size_t off = 0;
    auto alloc = [&](size_t bytes) -> char* {
        char* p = ws + off;
        off += (bytes + 255) & ~(size_t)255;
        return p;
    };
    float* xf  = (float*)alloc((size_t)NN * 128 * 4);        // 25.6 MB
    float* agg = (float*)alloc((size_t)NBINS * 128 * 4);     // 51.2 MB
    int* hist       = (int*)alloc((size_t)NBINS * 4);
    int* offs       = (int*)alloc((size_t)(NBINS + 1) * 4);
    int* cursor     = (int*)alloc((size_t)NBINS * 4);
    int* sorted_src = (int*)alloc((size_t)EE * 4);           // 6.4 MB
    int* bsum       = (int*)alloc((size_t)SCAN_NB * 4);
    int* boff       = (int*)alloc((size_t)SCAN_NB * 4);
    unsigned short* desHi = (unsigned short*)alloc((size_t)768 * 128 * 2);
    unsigned short* desLo = (unsigned short*)alloc((size_t)768 * 128 * 2);
    unsigned short* tweHi = (unsigned short*)alloc((size_t)768 * 128 * 2);
    unsigned short* tweLo = (unsigned short*)alloc((size_t)768 * 128 * 2);
    unsigned short* rootHi = (unsigned short*)alloc((size_t)2 * 16384 * 2);
    unsigned short* rootLo = (unsigned short*)alloc((size_t)2 * 16384 * 2);
    unsigned short* relHi  = (unsigned short*)alloc((size_t)4 * 16384 * 2);
    unsigned short* relLo  = (unsigned short*)alloc((size_t)4 * 16384 * 2);
    unsigned short* w1Hi   = (unsigned short*)alloc((size_t)16384 * 2);
    unsigned short* w1Lo   = (unsigned short*)alloc((size_t)16384 * 2);
    float* hf = agg;   // agg is dead once the MLP runs

    // ---- weight prep: single fused launch over all 9 segments ----
    {
        TRArgs a;
        const float* srcs[9] = { des_w, twe_w, root_w, root_w + 16384,
                                 rel_w, rel_w + 16384, rel_w + 2 * 16384, rel_w + 3 * 16384,
                                 mlp_w1 };
        unsigned short* his[9] = { desHi, tweHi, rootHi, rootHi + 16384,
                                   relHi, relHi + 16384, relHi + 2 * 16384, relHi + 3 * 16384,
                                   w1Hi };
        unsigned short* los[9] = { desLo, tweLo, rootLo, rootLo + 16384,
                                   relLo, relLo + 16384, relLo + 2 * 16384, relLo + 3 * 16384,
                                   w1Lo };
        const int Ks[9] = { 768, 768, 128, 128, 128, 128, 128, 128, 128 };
        int b = 0;
        for (int s = 0; s < 9; ++s) {
            a.src[s] = srcs[s]; a.dhi[s] = his[s]; a.dlo[s] = los[s]; a.K[s] = Ks[s];
            a.base[s] = b; b += Ks[s] * 128;
        }
        a.base[9] = b;   // 311296
        rg_tr_all<<<(b + 255) / 256, 256, 0, stream>>>(a);
    }

    // ---- edge sort (once; reused by both layers) ----
    hipMemsetAsync(hist, 0, (size_t)NBINS * 4, stream);
    rg_hist<<<(EE + 255) / 256, 256, 0, stream>>>(ei, et, hist);
    rg_scan_blk<<<SCAN_NB, 256, 0, stream>>>(hist, bsum);
    rg_scan_top<<<1, 512, 0, stream>>>(bsum, boff, offs);
    rg_scan_fin<<<SCAN_NB, 256, 0, stream>>>(hist, boff, offs, cursor);
    rg_place<<<(EE + 255) / 256, 256, 0, stream>>>(ei, et, cursor, sorted_src);

    const int bps = (NN + 63) / 64;  // 782

    // ---- projection: 3 segments in one launch, zero extra memory ----
    rg_part<<<3 * bps, 256, 0, stream>>>(
        twe, des, des,
        tweHi, desHi, desHi,
        tweLo, desLo, desLo,
        xf, agg, agg + (size_t)NN * 128,
        0, 0, 384,
        24, 12, 12,
        768, bps);
    rg_proj_fin<<<2048, 256, 0, stream>>>(xf, agg, agg + (size_t)NN * 128,
                                          num, cat, num_w, cat_w,
                                          des_b, twe_b, num_b, cat_b, xf);

    // ---- RGCN layers: gather-reduce + fused GEMM ----
    const int gather_grid = (NBINS * 64 + 255) / 256;
    for (int l = 0; l < 2; ++l) {
        rg_gather<<<gather_grid, 256, 0, stream>>>(xf, sorted_src, offs, agg);
        rg_gemm<<<bps, 256, 0, stream>>>(
            xf, agg, agg + (size_t)NN * 128,
            rootHi + (size_t)l * 16384, rootLo + (size_t)l * 16384,
            relHi + (size_t)(l * 2) * 16384, relLo + (size_t)(l * 2) * 16384,
            relHi + (size_t)(l * 2 + 1) * 16384, relLo + (size_t)(l * 2 + 1) * 16384,
            rgcn_b + l * 128, 3, 0, xf);
    }
    // ---- MLP layer 1 (relu) ----
    rg_gemm<<<bps, 256, 0, stream>>>(xf, nullptr, nullptr,
                                     w1Hi, w1Lo, nullptr, nullptr, nullptr, nullptr,
                                     mlp_b1, 1, 1, hf);
    // ---- head ----
    BotRGCN_64381559767213_kernel<<<2048, 256, 0, stream>>>(hf, mlp_w2, mlp_b2,
                                                            (float*)d_out);
}